// Round 1
// baseline (284.889 us; speedup 1.0000x reference)
//
#include <hip/hip_runtime.h>

#define NBINS    65536
#define MAXVOX   16000
#define MAXPTS   32
#define GRID_X   256
#define GRID_Y   256

// d_out layout (floats): voxels [16000*32*4] | coords [16000*3] | num_points [16000]
#define COORDS_OFF (MAXVOX * MAXPTS * 4)
#define NP_OFF     (COORDS_OFF + MAXVOX * 3)

// ws layout (bytes)
#define OFF_COUNTS   0u
#define OFF_CURSORS  (256u * 1024u)
#define OFF_STARTS   (512u * 1024u)
#define OFF_VIDMAP   (768u * 1024u)
#define OFF_BINOF    (1024u * 1024u)
#define OFF_PARTC    (OFF_BINOF + 64u * 1024u)
#define OFF_PARTO    (OFF_PARTC + 1024u)
#define OFF_BASEC    (OFF_PARTC + 2048u)
#define OFF_BASEO    (OFF_PARTC + 3072u)
#define OFF_BINS     (OFF_PARTC + 64u * 1024u)
#define OFF_MEMBERS  (OFF_BINS + 16u * 1024u * 1024u)

__global__ void k_count(const float4* __restrict__ pts, int n,
                        unsigned* __restrict__ counts, unsigned* __restrict__ bins) {
    int stride = gridDim.x * blockDim.x;
    for (int i = blockIdx.x * blockDim.x + threadIdx.x; i < n; i += stride) {
        float4 p = pts[i];
        bool valid = (p.x >= 0.0f)   & (p.x < 51.2f) &
                     (p.y >= -25.6f) & (p.y < 25.6f) &
                     (p.z >= -3.0f)  & (p.z < 5.0f);
        int cx = (int)floorf((p.x - 0.0f)   / 0.2f);
        int cy = (int)floorf((p.y + 25.6f)  / 0.2f);
        int cz = (int)floorf((p.z + 3.0f)   / 8.0f);
        cx = min(max(cx, 0), GRID_X - 1);
        cy = min(max(cy, 0), GRID_Y - 1);
        cz = min(max(cz, 0), 0);
        unsigned bin = (unsigned)(cx * (GRID_Y * 1) + cy * 1 + cz);
        if (valid) {
            bins[i] = bin;
            atomicAdd(&counts[bin], 1u);
        } else {
            bins[i] = 0xFFFFFFFFu;
        }
    }
}

// 256 blocks x 256 thr: per-block reduce of counts + occupancy
__global__ void k_scan1(const unsigned* __restrict__ counts,
                        unsigned* __restrict__ partC, unsigned* __restrict__ partO) {
    __shared__ unsigned sc[256], so[256];
    int t = threadIdx.x;
    unsigned c = counts[blockIdx.x * 256 + t];
    sc[t] = c; so[t] = (c > 0u) ? 1u : 0u;
    __syncthreads();
    for (int off = 128; off > 0; off >>= 1) {
        if (t < off) { sc[t] += sc[t + off]; so[t] += so[t + off]; }
        __syncthreads();
    }
    if (t == 0) { partC[blockIdx.x] = sc[0]; partO[blockIdx.x] = so[0]; }
}

// 1 block x 256: exclusive scan of the 256 block partials
__global__ void k_scan2(const unsigned* __restrict__ partC, const unsigned* __restrict__ partO,
                        unsigned* __restrict__ baseC, unsigned* __restrict__ baseO) {
    __shared__ unsigned sc[256], so[256];
    int t = threadIdx.x;
    unsigned mc = partC[t], mo = partO[t];
    sc[t] = mc; so[t] = mo;
    __syncthreads();
    for (int off = 1; off < 256; off <<= 1) {
        unsigned ac = (t >= off) ? sc[t - off] : 0u;
        unsigned ao = (t >= off) ? so[t - off] : 0u;
        __syncthreads();
        sc[t] += ac; so[t] += ao;
        __syncthreads();
    }
    baseC[t] = sc[t] - mc;   // exclusive
    baseO[t] = so[t] - mo;
}

// 256 blocks x 256: per-bin starts, vid assignment, coords/num_points outputs
__global__ void k_scan3(const unsigned* __restrict__ counts,
                        const unsigned* __restrict__ baseC, const unsigned* __restrict__ baseO,
                        unsigned* __restrict__ starts, unsigned* __restrict__ vidmap,
                        unsigned* __restrict__ binof, float* __restrict__ out) {
    __shared__ unsigned sc[256], so[256];
    int t = threadIdx.x;
    int bin = blockIdx.x * 256 + t;
    unsigned c = counts[bin];
    unsigned occ = (c > 0u) ? 1u : 0u;
    sc[t] = c; so[t] = occ;
    __syncthreads();
    for (int off = 1; off < 256; off <<= 1) {
        unsigned ac = (t >= off) ? sc[t - off] : 0u;
        unsigned ao = (t >= off) ? so[t - off] : 0u;
        __syncthreads();
        sc[t] += ac; so[t] += ao;
        __syncthreads();
    }
    starts[bin] = baseC[blockIdx.x] + (sc[t] - c);
    unsigned vid = baseO[blockIdx.x] + (so[t] - occ);
    vidmap[bin] = occ ? vid : 0xFFFFFFFFu;
    if (occ && vid < MAXVOX) {
        binof[vid] = (unsigned)bin;
        out[COORDS_OFF + vid * 3 + 0] = (float)(bin >> 8);
        out[COORDS_OFF + vid * 3 + 1] = (float)(bin & 255);
        out[COORDS_OFF + vid * 3 + 2] = 0.0f;
        out[NP_OFF + vid] = (float)(c < MAXPTS ? c : MAXPTS);
    }
}

__global__ void k_scatter(const unsigned* __restrict__ bins, int n,
                          const unsigned* __restrict__ vidmap, const unsigned* __restrict__ starts,
                          unsigned* __restrict__ cursors, unsigned* __restrict__ members) {
    int stride = gridDim.x * blockDim.x;
    for (int i = blockIdx.x * blockDim.x + threadIdx.x; i < n; i += stride) {
        unsigned b = bins[i];
        if (b == 0xFFFFFFFFu) continue;
        if (vidmap[b] >= MAXVOX) continue;   // voxel not kept
        unsigned pos = starts[b] + atomicAdd(&cursors[b], 1u);
        members[pos] = (unsigned)i;
    }
}

// one wave (64 thr) per kept voxel: exact rank of up to 256 member indices
__global__ __launch_bounds__(64) void k_select(
        const unsigned* __restrict__ binof, const unsigned* __restrict__ counts,
        const unsigned* __restrict__ starts, const unsigned* __restrict__ members,
        const float4* __restrict__ pts, float4* __restrict__ vox) {
    int v = blockIdx.x;
    unsigned bin = binof[v];
    if (bin == 0xFFFFFFFFu) return;
    unsigned m  = counts[bin];
    unsigned mc = m > 256u ? 256u : m;
    unsigned start = starts[bin];
    unsigned lane = threadIdx.x;

    unsigned e0 = (lane         < mc) ? members[start + lane]        : 0xFFFFFFFFu;
    unsigned e1 = (lane + 64u   < mc) ? members[start + lane + 64u]  : 0xFFFFFFFFu;
    unsigned e2 = (lane + 128u  < mc) ? members[start + lane + 128u] : 0xFFFFFFFFu;
    unsigned e3 = (lane + 192u  < mc) ? members[start + lane + 192u] : 0xFFFFFFFFu;

    unsigned r0 = 0, r1 = 0, r2 = 0, r3 = 0;
    for (int j = 0; j < 64; ++j) {
        unsigned a0 = (unsigned)__shfl((int)e0, j);
        unsigned a1 = (unsigned)__shfl((int)e1, j);
        unsigned a2 = (unsigned)__shfl((int)e2, j);
        unsigned a3 = (unsigned)__shfl((int)e3, j);
        r0 += (a0 < e0) + (a1 < e0) + (a2 < e0) + (a3 < e0);
        r1 += (a0 < e1) + (a1 < e1) + (a2 < e1) + (a3 < e1);
        r2 += (a0 < e2) + (a1 < e2) + (a2 < e2) + (a3 < e2);
        r3 += (a0 < e3) + (a1 < e3) + (a2 < e3) + (a3 < e3);
    }
    if (e0 != 0xFFFFFFFFu && r0 < MAXPTS) vox[(size_t)v * MAXPTS + r0] = pts[e0];
    if (e1 != 0xFFFFFFFFu && r1 < MAXPTS) vox[(size_t)v * MAXPTS + r1] = pts[e1];
    if (e2 != 0xFFFFFFFFu && r2 < MAXPTS) vox[(size_t)v * MAXPTS + r2] = pts[e2];
    if (e3 != 0xFFFFFFFFu && r3 < MAXPTS) vox[(size_t)v * MAXPTS + r3] = pts[e3];
}

extern "C" void kernel_launch(void* const* d_in, const int* in_sizes, int n_in,
                              void* d_out, int out_size, void* d_ws, size_t ws_size,
                              hipStream_t stream) {
    const float4* pts = (const float4*)d_in[0];
    int n = in_sizes[0] / 4;
    float* out = (float*)d_out;
    char* ws = (char*)d_ws;

    unsigned* counts  = (unsigned*)(ws + OFF_COUNTS);
    unsigned* cursors = (unsigned*)(ws + OFF_CURSORS);
    unsigned* starts  = (unsigned*)(ws + OFF_STARTS);
    unsigned* vidmap  = (unsigned*)(ws + OFF_VIDMAP);
    unsigned* binof   = (unsigned*)(ws + OFF_BINOF);
    unsigned* partC   = (unsigned*)(ws + OFF_PARTC);
    unsigned* partO   = (unsigned*)(ws + OFF_PARTO);
    unsigned* baseC   = (unsigned*)(ws + OFF_BASEC);
    unsigned* baseO   = (unsigned*)(ws + OFF_BASEO);
    unsigned* bins    = (unsigned*)(ws + OFF_BINS);
    unsigned* members = (unsigned*)(ws + OFF_MEMBERS);

    hipMemsetAsync(d_out, 0, (size_t)out_size * sizeof(float), stream);
    hipMemsetAsync(counts, 0, 2u * NBINS * sizeof(unsigned), stream); // counts + cursors
    hipMemsetAsync(binof, 0xFF, MAXVOX * sizeof(unsigned), stream);

    k_count  <<<2048, 256, 0, stream>>>(pts, n, counts, bins);
    k_scan1  <<<256, 256, 0, stream>>>(counts, partC, partO);
    k_scan2  <<<1, 256, 0, stream>>>(partC, partO, baseC, baseO);
    k_scan3  <<<256, 256, 0, stream>>>(counts, baseC, baseO, starts, vidmap, binof, out);
    k_scatter<<<2048, 256, 0, stream>>>(bins, n, vidmap, starts, cursors, members);
    k_select <<<MAXVOX, 64, 0, stream>>>(binof, counts, starts, members, pts, (float4*)d_out);
}

// Round 2
// 130.279 us; speedup vs baseline: 2.1868x; 2.1868x over previous
//
#include <hip/hip_runtime.h>

#define NBINS    65536
#define NWORDS   16384        // NBINS/4, u8x4 packed
#define MAXVOX   16000
#define MAXPTS   32
#define NBLK     256          // hist/scatter blocks (contiguous point chunks)

// d_out layout (floats): voxels [16000*32*4] | coords [16000*3] | num_points [16000]
#define COORDS_OFF (MAXVOX * MAXPTS * 4)
#define NP_OFF     (COORDS_OFF + MAXVOX * 3)

// ws layout (bytes)
#define OFF_COUNTS   0u              // u32[65536]  256KB
#define OFF_STARTS   (256u << 10)    // u32[65536]  256KB (bit31 = NOT-kept flag)
#define OFF_BINOF    (512u << 10)    // u32[16000]   64KB
#define OFF_PARTC    (576u << 10)    // u32[256]      1KB
#define OFF_PARTO    (577u << 10)
#define OFF_BASEC    (578u << 10)
#define OFF_BASEO    (579u << 10)
#define OFF_BINS     (1u << 20)      // u32[4M]      16MB
#define OFF_PARTIAL  (17u << 20)     // u32[256][16384] 16MB (u8x4 packed)
#define OFF_MEMBERS  (33u << 20)     // u32[4M]      16MB

// ---------------- pass 1: per-block private histogram (u8x4 in LDS) ----------
__global__ __launch_bounds__(256) void k_hist(const float4* __restrict__ pts, int n,
                                              unsigned* __restrict__ bins,
                                              unsigned* __restrict__ partial) {
    __shared__ unsigned sh[NWORDS];  // 64 KiB
    int t = threadIdx.x, b = blockIdx.x;
    for (int w = t; w < NWORDS; w += 256) sh[w] = 0u;
    __syncthreads();

    int chunk = (n + NBLK - 1) / NBLK;
    int s = b * chunk;
    int e = min(n, s + chunk);
    for (int i = s + t; i < e; i += 256) {
        float4 p = pts[i];
        bool valid = (p.x >= 0.0f)   & (p.x < 51.2f) &
                     (p.y >= -25.6f) & (p.y < 25.6f) &
                     (p.z >= -3.0f)  & (p.z < 5.0f);
        int cx = (int)floorf((p.x - 0.0f)  / 0.2f);
        int cy = (int)floorf((p.y + 25.6f) / 0.2f);
        int cz = (int)floorf((p.z + 3.0f)  / 8.0f);
        cx = min(max(cx, 0), 255);
        cy = min(max(cy, 0), 255);
        cz = min(max(cz, 0), 0);
        unsigned bin = (unsigned)(cx * 256 + cy + cz);
        if (valid) {
            bins[i] = bin;
            atomicAdd(&sh[bin >> 2], 1u << ((bin & 3u) * 8u));
        } else {
            bins[i] = 0xFFFFFFFFu;
        }
    }
    __syncthreads();
    unsigned* myp = partial + (size_t)b * NWORDS;
    for (int w = t; w < NWORDS; w += 256) myp[w] = sh[w];
}

// ------- pass 2: column-sum partials -> counts; rewrite partials as exclusive
//         per-block byte prefixes; fused per-256-bin reduction (old scan1) ----
__global__ __launch_bounds__(64) void k_reduce(unsigned* __restrict__ partial,
                                               unsigned* __restrict__ counts,
                                               unsigned* __restrict__ partC,
                                               unsigned* __restrict__ partO) {
    int w = blockIdx.x * 64 + threadIdx.x;   // one word = 4 bins; block covers 256 bins
    unsigned a0 = 0, a1 = 0, a2 = 0, a3 = 0;
    for (int blk = 0; blk < NBLK; ++blk) {
        size_t idx = (size_t)blk * NWORDS + w;
        unsigned v = partial[idx];
        partial[idx] = a0 | (a1 << 8) | (a2 << 16) | (a3 << 24);  // exclusive prefix (u8-safe)
        a0 += v & 255u; a1 += (v >> 8) & 255u;
        a2 += (v >> 16) & 255u; a3 += (v >> 24) & 255u;
    }
    counts[w * 4 + 0] = a0;
    counts[w * 4 + 1] = a1;
    counts[w * 4 + 2] = a2;
    counts[w * 4 + 3] = a3;

    unsigned mySum = a0 + a1 + a2 + a3;
    unsigned myOcc = (a0 > 0u) + (a1 > 0u) + (a2 > 0u) + (a3 > 0u);
    for (int off = 32; off > 0; off >>= 1) {
        mySum += __shfl_down(mySum, off);
        myOcc += __shfl_down(myOcc, off);
    }
    if (threadIdx.x == 0) { partC[blockIdx.x] = mySum; partO[blockIdx.x] = myOcc; }
}

// 1 block x 256: exclusive scan of the 256 block partials
__global__ void k_scan2(const unsigned* __restrict__ partC, const unsigned* __restrict__ partO,
                        unsigned* __restrict__ baseC, unsigned* __restrict__ baseO) {
    __shared__ unsigned sc[256], so[256];
    int t = threadIdx.x;
    unsigned mc = partC[t], mo = partO[t];
    sc[t] = mc; so[t] = mo;
    __syncthreads();
    for (int off = 1; off < 256; off <<= 1) {
        unsigned ac = (t >= off) ? sc[t - off] : 0u;
        unsigned ao = (t >= off) ? so[t - off] : 0u;
        __syncthreads();
        sc[t] += ac; so[t] += ao;
        __syncthreads();
    }
    baseC[t] = sc[t] - mc;   // exclusive
    baseO[t] = so[t] - mo;
}

// per-bin starts (bit31 = not-kept), vid assignment, coords/num_points outputs
__global__ void k_scan3(const unsigned* __restrict__ counts,
                        const unsigned* __restrict__ baseC, const unsigned* __restrict__ baseO,
                        unsigned* __restrict__ starts, unsigned* __restrict__ binof,
                        float* __restrict__ out) {
    __shared__ unsigned sc[256], so[256];
    int t = threadIdx.x;
    int bin = blockIdx.x * 256 + t;
    unsigned c = counts[bin];
    unsigned occ = (c > 0u) ? 1u : 0u;
    sc[t] = c; so[t] = occ;
    __syncthreads();
    for (int off = 1; off < 256; off <<= 1) {
        unsigned ac = (t >= off) ? sc[t - off] : 0u;
        unsigned ao = (t >= off) ? so[t - off] : 0u;
        __syncthreads();
        sc[t] += ac; so[t] += ao;
        __syncthreads();
    }
    unsigned st  = baseC[blockIdx.x] + (sc[t] - c);
    unsigned vid = baseO[blockIdx.x] + (so[t] - occ);
    bool kept = occ && (vid < MAXVOX);
    starts[bin] = st | (kept ? 0u : 0x80000000u);
    if (kept) {
        binof[vid] = (unsigned)bin;
        out[COORDS_OFF + vid * 3 + 0] = (float)(bin >> 8);
        out[COORDS_OFF + vid * 3 + 1] = (float)(bin & 255);
        out[COORDS_OFF + vid * 3 + 2] = 0.0f;
        out[NP_OFF + vid] = (float)(c < MAXPTS ? c : MAXPTS);
    }
}

// ---- pass 3: scatter via LDS byte-cursors seeded with per-block prefixes ----
__global__ __launch_bounds__(256) void k_scatter(const unsigned* __restrict__ bins, int n,
                                                 const unsigned* __restrict__ partial,
                                                 const unsigned* __restrict__ starts,
                                                 unsigned* __restrict__ members) {
    __shared__ unsigned sh[NWORDS];  // 64 KiB byte-cursors, seeded with exclusive prefix
    int t = threadIdx.x, b = blockIdx.x;
    const unsigned* myp = partial + (size_t)b * NWORDS;
    for (int w = t; w < NWORDS; w += 256) sh[w] = myp[w];
    __syncthreads();

    int chunk = (n + NBLK - 1) / NBLK;
    int s = b * chunk;
    int e = min(n, s + chunk);
    for (int i = s + t; i < e; i += 256) {
        unsigned v = bins[i];
        if (v == 0xFFFFFFFFu) continue;
        unsigned st = starts[v];
        if (st & 0x80000000u) continue;            // voxel not kept
        unsigned old = atomicAdd(&sh[v >> 2], 1u << ((v & 3u) * 8u));
        unsigned off = (old >> ((v & 3u) * 8u)) & 255u;
        members[st + off] = (unsigned)i;
    }
}

// ---- pass 4: one wave per kept voxel, exact rank of member indices ----------
__global__ __launch_bounds__(64) void k_select(
        const unsigned* __restrict__ binof, const unsigned* __restrict__ counts,
        const unsigned* __restrict__ starts, const unsigned* __restrict__ members,
        const float4* __restrict__ pts, float4* __restrict__ vox) {
    int v = blockIdx.x;
    unsigned bin = binof[v];
    if (bin == 0xFFFFFFFFu) return;
    unsigned m  = counts[bin];
    unsigned mc = m > 256u ? 256u : m;
    unsigned start = starts[bin] & 0x7FFFFFFFu;
    unsigned lane = threadIdx.x;

    if (mc <= 64u) {
        unsigned e0 = (lane < mc) ? members[start + lane] : 0xFFFFFFFFu;
        unsigned r0 = 0;
        int jm = (int)mc;
        for (int j = 0; j < jm; ++j) {
            unsigned a0 = (unsigned)__shfl((int)e0, j);
            r0 += (a0 < e0);
        }
        if (e0 != 0xFFFFFFFFu && r0 < MAXPTS) vox[(size_t)v * MAXPTS + r0] = pts[e0];
    } else if (mc <= 128u) {
        unsigned e0 = members[start + lane];
        unsigned e1 = (lane + 64u < mc) ? members[start + lane + 64u] : 0xFFFFFFFFu;
        unsigned r0 = 0, r1 = 0;
        for (int j = 0; j < 64; ++j) {
            unsigned a0 = (unsigned)__shfl((int)e0, j);
            unsigned a1 = (unsigned)__shfl((int)e1, j);
            r0 += (a0 < e0) + (a1 < e0);
            r1 += (a0 < e1) + (a1 < e1);
        }
        if (r0 < MAXPTS) vox[(size_t)v * MAXPTS + r0] = pts[e0];
        if (e1 != 0xFFFFFFFFu && r1 < MAXPTS) vox[(size_t)v * MAXPTS + r1] = pts[e1];
    } else {
        unsigned e0 = members[start + lane];
        unsigned e1 = members[start + lane + 64u];
        unsigned e2 = (lane + 128u < mc) ? members[start + lane + 128u] : 0xFFFFFFFFu;
        unsigned e3 = (lane + 192u < mc) ? members[start + lane + 192u] : 0xFFFFFFFFu;
        unsigned r0 = 0, r1 = 0, r2 = 0, r3 = 0;
        for (int j = 0; j < 64; ++j) {
            unsigned a0 = (unsigned)__shfl((int)e0, j);
            unsigned a1 = (unsigned)__shfl((int)e1, j);
            unsigned a2 = (unsigned)__shfl((int)e2, j);
            unsigned a3 = (unsigned)__shfl((int)e3, j);
            r0 += (a0 < e0) + (a1 < e0) + (a2 < e0) + (a3 < e0);
            r1 += (a0 < e1) + (a1 < e1) + (a2 < e1) + (a3 < e1);
            r2 += (a0 < e2) + (a1 < e2) + (a2 < e2) + (a3 < e2);
            r3 += (a0 < e3) + (a1 < e3) + (a2 < e3) + (a3 < e3);
        }
        if (r0 < MAXPTS) vox[(size_t)v * MAXPTS + r0] = pts[e0];
        if (r1 < MAXPTS) vox[(size_t)v * MAXPTS + r1] = pts[e1];
        if (e2 != 0xFFFFFFFFu && r2 < MAXPTS) vox[(size_t)v * MAXPTS + r2] = pts[e2];
        if (e3 != 0xFFFFFFFFu && r3 < MAXPTS) vox[(size_t)v * MAXPTS + r3] = pts[e3];
    }
}

extern "C" void kernel_launch(void* const* d_in, const int* in_sizes, int n_in,
                              void* d_out, int out_size, void* d_ws, size_t ws_size,
                              hipStream_t stream) {
    const float4* pts = (const float4*)d_in[0];
    int n = in_sizes[0] / 4;
    float* out = (float*)d_out;
    char* ws = (char*)d_ws;

    unsigned* counts  = (unsigned*)(ws + OFF_COUNTS);
    unsigned* starts  = (unsigned*)(ws + OFF_STARTS);
    unsigned* binof   = (unsigned*)(ws + OFF_BINOF);
    unsigned* partC   = (unsigned*)(ws + OFF_PARTC);
    unsigned* partO   = (unsigned*)(ws + OFF_PARTO);
    unsigned* baseC   = (unsigned*)(ws + OFF_BASEC);
    unsigned* baseO   = (unsigned*)(ws + OFF_BASEO);
    unsigned* bins    = (unsigned*)(ws + OFF_BINS);
    unsigned* partial = (unsigned*)(ws + OFF_PARTIAL);
    unsigned* members = (unsigned*)(ws + OFF_MEMBERS);

    hipMemsetAsync(d_out, 0, (size_t)out_size * sizeof(float), stream);
    hipMemsetAsync(binof, 0xFF, MAXVOX * sizeof(unsigned), stream);

    k_hist   <<<NBLK, 256, 0, stream>>>(pts, n, bins, partial);
    k_reduce <<<NWORDS / 64, 64, 0, stream>>>(partial, counts, partC, partO);
    k_scan2  <<<1, 256, 0, stream>>>(partC, partO, baseC, baseO);
    k_scan3  <<<256, 256, 0, stream>>>(counts, baseC, baseO, starts, binof, out);
    k_scatter<<<NBLK, 256, 0, stream>>>(bins, n, partial, starts, members);
    k_select <<<MAXVOX, 64, 0, stream>>>(binof, counts, starts, members, pts, (float4*)d_out);
}

// Round 3
// 87.291 us; speedup vs baseline: 3.2637x; 1.4925x over previous
//
#include <hip/hip_runtime.h>

#define NBINS    65536
#define NWORDS   16384        // NBINS/4, u8x4 packed
#define MAXVOX   16000
#define MAXPTS   32
#define NBLK     256          // hist/scatter blocks (contiguous point chunks)
#define RSEG     8            // k_reduce segments (NBLK/RSEG source-blocks each)

// d_out layout (floats): voxels [16000*32*4] | coords [16000*3] | num_points [16000]
#define COORDS_OFF (MAXVOX * MAXPTS * 4)
#define NP_OFF     (COORDS_OFF + MAXVOX * 3)

// ws layout (bytes)
#define OFF_COUNTS   0u              // u32[65536]  256KB
#define OFF_STARTS   (256u << 10)    // u32[65536]  256KB (bit31 = NOT-kept flag)
#define OFF_BINOF    (512u << 10)    // u32[16000]   64KB
#define OFF_PARTC    (576u << 10)    // u32[256]      1KB
#define OFF_PARTO    (577u << 10)
#define OFF_BASEC    (578u << 10)
#define OFF_BASEO    (579u << 10)
#define OFF_BINS     (1u << 20)      // u32[4M]      16MB
#define OFF_PARTIAL  (17u << 20)     // u32[256][16384] 16MB (u8x4 packed)
#define OFF_MEMBERS  (33u << 20)     // u32[4M]      16MB

// ---------------- pass 1: per-block private histogram (u8x4 in LDS) ----------
__global__ __launch_bounds__(1024) void k_hist(const float4* __restrict__ pts, int n,
                                               unsigned* __restrict__ bins,
                                               unsigned* __restrict__ partial) {
    __shared__ unsigned sh[NWORDS];  // 64 KiB
    int t = threadIdx.x, b = blockIdx.x;
    for (int w = t; w < NWORDS; w += 1024) sh[w] = 0u;
    __syncthreads();

    int chunk = (n + NBLK - 1) / NBLK;
    int s = b * chunk;
    int e = min(n, s + chunk);
    for (int i = s + t; i < e; i += 1024) {
        float4 p = pts[i];
        bool valid = (p.x >= 0.0f)   & (p.x < 51.2f) &
                     (p.y >= -25.6f) & (p.y < 25.6f) &
                     (p.z >= -3.0f)  & (p.z < 5.0f);
        int cx = (int)floorf((p.x - 0.0f)  / 0.2f);
        int cy = (int)floorf((p.y + 25.6f) / 0.2f);
        int cz = (int)floorf((p.z + 3.0f)  / 8.0f);
        cx = min(max(cx, 0), 255);
        cy = min(max(cy, 0), 255);
        cz = min(max(cz, 0), 0);
        unsigned bin = (unsigned)(cx * 256 + cy + cz);
        if (valid) {
            bins[i] = bin;
            atomicAdd(&sh[bin >> 2], 1u << ((bin & 3u) * 8u));
        } else {
            bins[i] = 0xFFFFFFFFu;
        }
    }
    __syncthreads();
    unsigned* myp = partial + (size_t)b * NWORDS;
    for (int w = t; w < NWORDS; w += 1024) myp[w] = sh[w];
}

// ------- pass 2: column-sum partials -> counts; rewrite partials as exclusive
//         per-block byte prefixes. 256 blocks x 512 thr; each block owns 64
//         words; 8 segments of 32 source-blocks each (chain length 32). ------
__global__ __launch_bounds__(512) void k_reduce(unsigned* __restrict__ partial,
                                                unsigned* __restrict__ counts,
                                                unsigned* __restrict__ partC,
                                                unsigned* __restrict__ partO) {
    __shared__ unsigned segsum[RSEG][64][4];   // 8 KiB
    __shared__ unsigned red[512];
    int t = threadIdx.x;
    int wl  = t & 63;                 // word within this block's 64-word group
    int seg = t >> 6;                 // 0..7
    int w   = blockIdx.x * 64 + wl;   // global word
    int blk0 = seg * (NBLK / RSEG);   // 32 source-blocks per segment

    unsigned a0 = 0, a1 = 0, a2 = 0, a3 = 0;
    for (int b = 0; b < NBLK / RSEG; ++b) {
        unsigned v = partial[(size_t)(blk0 + b) * NWORDS + w];
        a0 += v & 255u; a1 += (v >> 8) & 255u;
        a2 += (v >> 16) & 255u; a3 += (v >> 24) & 255u;
    }
    segsum[seg][wl][0] = a0; segsum[seg][wl][1] = a1;
    segsum[seg][wl][2] = a2; segsum[seg][wl][3] = a3;
    __syncthreads();

    unsigned b0 = 0, b1 = 0, b2 = 0, b3 = 0;
    for (int s2 = 0; s2 < seg; ++s2) {
        b0 += segsum[s2][wl][0]; b1 += segsum[s2][wl][1];
        b2 += segsum[s2][wl][2]; b3 += segsum[s2][wl][3];
    }
    for (int b = 0; b < NBLK / RSEG; ++b) {
        size_t idx = (size_t)(blk0 + b) * NWORDS + w;
        unsigned v = partial[idx];
        partial[idx] = b0 | (b1 << 8) | (b2 << 16) | (b3 << 24);  // u8-safe (totals < 256)
        b0 += v & 255u; b1 += (v >> 8) & 255u;
        b2 += (v >> 16) & 255u; b3 += (v >> 24) & 255u;
    }

    unsigned mySum = 0, myOcc = 0;
    if (seg == RSEG - 1) {            // b0..b3 are now the full per-bin totals
        counts[w * 4 + 0] = b0; counts[w * 4 + 1] = b1;
        counts[w * 4 + 2] = b2; counts[w * 4 + 3] = b3;
        mySum = b0 + b1 + b2 + b3;
        myOcc = (b0 > 0u) + (b1 > 0u) + (b2 > 0u) + (b3 > 0u);
    }
    red[t] = mySum; __syncthreads();
    for (int off = 256; off > 0; off >>= 1) { if (t < off) red[t] += red[t + off]; __syncthreads(); }
    if (t == 0) partC[blockIdx.x] = red[0];
    __syncthreads();
    red[t] = myOcc; __syncthreads();
    for (int off = 256; off > 0; off >>= 1) { if (t < off) red[t] += red[t + off]; __syncthreads(); }
    if (t == 0) partO[blockIdx.x] = red[0];
}

// 1 block x 256: exclusive scan of the 256 group partials
__global__ void k_scan2(const unsigned* __restrict__ partC, const unsigned* __restrict__ partO,
                        unsigned* __restrict__ baseC, unsigned* __restrict__ baseO) {
    __shared__ unsigned sc[256], so[256];
    int t = threadIdx.x;
    unsigned mc = partC[t], mo = partO[t];
    sc[t] = mc; so[t] = mo;
    __syncthreads();
    for (int off = 1; off < 256; off <<= 1) {
        unsigned ac = (t >= off) ? sc[t - off] : 0u;
        unsigned ao = (t >= off) ? so[t - off] : 0u;
        __syncthreads();
        sc[t] += ac; so[t] += ao;
        __syncthreads();
    }
    baseC[t] = sc[t] - mc;   // exclusive
    baseO[t] = so[t] - mo;
}

// per-bin starts (bit31 = not-kept), vid assignment, coords/num_points outputs
__global__ void k_scan3(const unsigned* __restrict__ counts,
                        const unsigned* __restrict__ baseC, const unsigned* __restrict__ baseO,
                        unsigned* __restrict__ starts, unsigned* __restrict__ binof,
                        float* __restrict__ out) {
    __shared__ unsigned sc[256], so[256];
    int t = threadIdx.x;
    int bin = blockIdx.x * 256 + t;
    unsigned c = counts[bin];
    unsigned occ = (c > 0u) ? 1u : 0u;
    sc[t] = c; so[t] = occ;
    __syncthreads();
    for (int off = 1; off < 256; off <<= 1) {
        unsigned ac = (t >= off) ? sc[t - off] : 0u;
        unsigned ao = (t >= off) ? so[t - off] : 0u;
        __syncthreads();
        sc[t] += ac; so[t] += ao;
        __syncthreads();
    }
    unsigned st  = baseC[blockIdx.x] + (sc[t] - c);
    unsigned vid = baseO[blockIdx.x] + (so[t] - occ);
    bool kept = occ && (vid < MAXVOX);
    starts[bin] = st | (kept ? 0u : 0x80000000u);
    if (kept) {
        binof[vid] = (unsigned)bin;
        out[COORDS_OFF + vid * 3 + 0] = (float)(bin >> 8);
        out[COORDS_OFF + vid * 3 + 1] = (float)(bin & 255);
        out[COORDS_OFF + vid * 3 + 2] = 0.0f;
        out[NP_OFF + vid] = (float)(c < MAXPTS ? c : MAXPTS);
    }
}

// ---- pass 3: scatter via LDS byte-cursors seeded with per-block prefixes ----
__global__ __launch_bounds__(1024) void k_scatter(const unsigned* __restrict__ bins, int n,
                                                  const unsigned* __restrict__ partial,
                                                  const unsigned* __restrict__ starts,
                                                  unsigned* __restrict__ members) {
    __shared__ unsigned sh[NWORDS];  // 64 KiB byte-cursors, seeded with exclusive prefix
    int t = threadIdx.x, b = blockIdx.x;
    const unsigned* myp = partial + (size_t)b * NWORDS;
    for (int w = t; w < NWORDS; w += 1024) sh[w] = myp[w];
    __syncthreads();

    int chunk = (n + NBLK - 1) / NBLK;
    int s = b * chunk;
    int e = min(n, s + chunk);
    for (int i = s + t; i < e; i += 1024) {
        unsigned v = bins[i];
        if (v == 0xFFFFFFFFu) continue;
        unsigned st = starts[v];
        if (st & 0x80000000u) continue;            // voxel not kept
        unsigned old = atomicAdd(&sh[v >> 2], 1u << ((v & 3u) * 8u));
        unsigned off = (old >> ((v & 3u) * 8u)) & 255u;
        members[st + off] = (unsigned)i;
    }
}

// ---- pass 4: one wave per kept voxel (4 voxels/block), exact index rank -----
__global__ __launch_bounds__(256) void k_select(
        const unsigned* __restrict__ binof, const unsigned* __restrict__ counts,
        const unsigned* __restrict__ starts, const unsigned* __restrict__ members,
        const float4* __restrict__ pts, float4* __restrict__ vox) {
    int v = blockIdx.x * 4 + (threadIdx.x >> 6);
    unsigned lane = threadIdx.x & 63u;
    unsigned bin = binof[v];
    if (bin == 0xFFFFFFFFu) return;
    unsigned m  = counts[bin];
    unsigned mc = m > 256u ? 256u : m;
    unsigned start = starts[bin] & 0x7FFFFFFFu;

    if (mc <= 64u) {
        unsigned e0 = (lane < mc) ? members[start + lane] : 0xFFFFFFFFu;
        unsigned r0 = 0;
        int jm = (int)mc;
        for (int j = 0; j < jm; ++j) {
            unsigned a0 = (unsigned)__shfl((int)e0, j);
            r0 += (a0 < e0);
        }
        if (e0 != 0xFFFFFFFFu && r0 < MAXPTS) vox[(size_t)v * MAXPTS + r0] = pts[e0];
    } else if (mc <= 128u) {
        unsigned e0 = members[start + lane];
        unsigned e1 = (lane + 64u < mc) ? members[start + lane + 64u] : 0xFFFFFFFFu;
        unsigned r0 = 0, r1 = 0;
        for (int j = 0; j < 64; ++j) {
            unsigned a0 = (unsigned)__shfl((int)e0, j);
            unsigned a1 = (unsigned)__shfl((int)e1, j);
            r0 += (a0 < e0) + (a1 < e0);
            r1 += (a0 < e1) + (a1 < e1);
        }
        if (r0 < MAXPTS) vox[(size_t)v * MAXPTS + r0] = pts[e0];
        if (e1 != 0xFFFFFFFFu && r1 < MAXPTS) vox[(size_t)v * MAXPTS + r1] = pts[e1];
    } else {
        unsigned e0 = members[start + lane];
        unsigned e1 = members[start + lane + 64u];
        unsigned e2 = (lane + 128u < mc) ? members[start + lane + 128u] : 0xFFFFFFFFu;
        unsigned e3 = (lane + 192u < mc) ? members[start + lane + 192u] : 0xFFFFFFFFu;
        unsigned r0 = 0, r1 = 0, r2 = 0, r3 = 0;
        for (int j = 0; j < 64; ++j) {
            unsigned a0 = (unsigned)__shfl((int)e0, j);
            unsigned a1 = (unsigned)__shfl((int)e1, j);
            unsigned a2 = (unsigned)__shfl((int)e2, j);
            unsigned a3 = (unsigned)__shfl((int)e3, j);
            r0 += (a0 < e0) + (a1 < e0) + (a2 < e0) + (a3 < e0);
            r1 += (a0 < e1) + (a1 < e1) + (a2 < e1) + (a3 < e1);
            r2 += (a0 < e2) + (a1 < e2) + (a2 < e2) + (a3 < e2);
            r3 += (a0 < e3) + (a1 < e3) + (a2 < e3) + (a3 < e3);
        }
        if (r0 < MAXPTS) vox[(size_t)v * MAXPTS + r0] = pts[e0];
        if (r1 < MAXPTS) vox[(size_t)v * MAXPTS + r1] = pts[e1];
        if (e2 != 0xFFFFFFFFu && r2 < MAXPTS) vox[(size_t)v * MAXPTS + r2] = pts[e2];
        if (e3 != 0xFFFFFFFFu && r3 < MAXPTS) vox[(size_t)v * MAXPTS + r3] = pts[e3];
    }
}

extern "C" void kernel_launch(void* const* d_in, const int* in_sizes, int n_in,
                              void* d_out, int out_size, void* d_ws, size_t ws_size,
                              hipStream_t stream) {
    const float4* pts = (const float4*)d_in[0];
    int n = in_sizes[0] / 4;
    float* out = (float*)d_out;
    char* ws = (char*)d_ws;

    unsigned* counts  = (unsigned*)(ws + OFF_COUNTS);
    unsigned* starts  = (unsigned*)(ws + OFF_STARTS);
    unsigned* binof   = (unsigned*)(ws + OFF_BINOF);
    unsigned* partC   = (unsigned*)(ws + OFF_PARTC);
    unsigned* partO   = (unsigned*)(ws + OFF_PARTO);
    unsigned* baseC   = (unsigned*)(ws + OFF_BASEC);
    unsigned* baseO   = (unsigned*)(ws + OFF_BASEO);
    unsigned* bins    = (unsigned*)(ws + OFF_BINS);
    unsigned* partial = (unsigned*)(ws + OFF_PARTIAL);
    unsigned* members = (unsigned*)(ws + OFF_MEMBERS);

    hipMemsetAsync(d_out, 0, (size_t)out_size * sizeof(float), stream);
    hipMemsetAsync(binof, 0xFF, MAXVOX * sizeof(unsigned), stream);

    k_hist   <<<NBLK, 1024, 0, stream>>>(pts, n, bins, partial);
    k_reduce <<<NWORDS / 64, 512, 0, stream>>>(partial, counts, partC, partO);
    k_scan2  <<<1, 256, 0, stream>>>(partC, partO, baseC, baseO);
    k_scan3  <<<256, 256, 0, stream>>>(counts, baseC, baseO, starts, binof, out);
    k_scatter<<<NBLK, 1024, 0, stream>>>(bins, n, partial, starts, members);
    k_select <<<MAXVOX / 4, 256, 0, stream>>>(binof, counts, starts, members, pts, (float4*)d_out);
}

// Round 4
// 76.808 us; speedup vs baseline: 3.7091x; 1.1365x over previous
//
#include <hip/hip_runtime.h>

#define NBINS    65536
#define NWORDS   16384        // NBINS/4, u8x4 packed
#define MAXVOX   16000
#define MAXPTS   32
#define NBLK     256          // hist/scatter blocks (contiguous point chunks)
#define RSEG     8            // k_reduce segments (NBLK/RSEG source-blocks each)

// d_out layout (floats): voxels [16000*32*4] | coords [16000*3] | num_points [16000]
#define COORDS_OFF (MAXVOX * MAXPTS * 4)
#define NP_OFF     (COORDS_OFF + MAXVOX * 3)

// ws layout (bytes)
#define OFF_COUNTS   0u              // u32[65536]  256KB
#define OFF_STARTS   (256u << 10)    // u32[65536]  256KB (bit31 = NOT-kept flag)
#define OFF_BINOF    (512u << 10)    // u32[16000]   64KB
#define OFF_PARTC    (576u << 10)    // u32[256]      1KB
#define OFF_PARTO    (577u << 10)
#define OFF_BINS     (1u << 20)      // u32[4M]      16MB
#define OFF_PARTIAL  (17u << 20)     // u32[256][16384] 16MB (u8x4 packed)
#define OFF_MEMBERS  (33u << 20)     // u32[4M]      16MB

// ---------------- pass 1: per-block private histogram (u8x4 in LDS) ----------
__global__ __launch_bounds__(1024) void k_hist(const float4* __restrict__ pts, int n,
                                               unsigned* __restrict__ bins,
                                               unsigned* __restrict__ partial) {
    __shared__ unsigned sh[NWORDS];  // 64 KiB
    int t = threadIdx.x, b = blockIdx.x;
    for (int w = t; w < NWORDS; w += 1024) sh[w] = 0u;
    __syncthreads();

    int chunk = (n + NBLK - 1) / NBLK;
    int s = b * chunk;
    int e = min(n, s + chunk);
    for (int i = s + t; i < e; i += 1024) {
        float4 p = pts[i];
        bool valid = (p.x >= 0.0f)   & (p.x < 51.2f) &
                     (p.y >= -25.6f) & (p.y < 25.6f) &
                     (p.z >= -3.0f)  & (p.z < 5.0f);
        int cx = (int)floorf((p.x - 0.0f)  / 0.2f);
        int cy = (int)floorf((p.y + 25.6f) / 0.2f);
        int cz = (int)floorf((p.z + 3.0f)  / 8.0f);
        cx = min(max(cx, 0), 255);
        cy = min(max(cy, 0), 255);
        cz = min(max(cz, 0), 0);
        unsigned bin = (unsigned)(cx * 256 + cy + cz);
        if (valid) {
            bins[i] = bin;
            atomicAdd(&sh[bin >> 2], 1u << ((bin & 3u) * 8u));
        } else {
            bins[i] = 0xFFFFFFFFu;
        }
    }
    __syncthreads();
    unsigned* myp = partial + (size_t)b * NWORDS;
    for (int w = t; w < NWORDS; w += 1024) myp[w] = sh[w];
}

// ------- pass 2: column-sum partials -> counts; rewrite partials as exclusive
//         per-block byte prefixes. 256 blocks x 512 thr; each block owns 64
//         words; 8 segments of 32 source-blocks each. Also inits binof. ------
__global__ __launch_bounds__(512) void k_reduce(unsigned* __restrict__ partial,
                                                unsigned* __restrict__ counts,
                                                unsigned* __restrict__ partC,
                                                unsigned* __restrict__ partO,
                                                unsigned* __restrict__ binof) {
    __shared__ unsigned segsum[RSEG][64][4];   // 8 KiB
    __shared__ unsigned red[512];
    int t = threadIdx.x;
    int g = blockIdx.x * 512 + t;
    if (g < MAXVOX) binof[g] = 0xFFFFFFFFu;    // runs before k_scan3 overwrites kept

    int wl  = t & 63;                 // word within this block's 64-word group
    int seg = t >> 6;                 // 0..7
    int w   = blockIdx.x * 64 + wl;   // global word
    int blk0 = seg * (NBLK / RSEG);   // 32 source-blocks per segment

    unsigned a0 = 0, a1 = 0, a2 = 0, a3 = 0;
    for (int b = 0; b < NBLK / RSEG; ++b) {
        unsigned v = partial[(size_t)(blk0 + b) * NWORDS + w];
        a0 += v & 255u; a1 += (v >> 8) & 255u;
        a2 += (v >> 16) & 255u; a3 += (v >> 24) & 255u;
    }
    segsum[seg][wl][0] = a0; segsum[seg][wl][1] = a1;
    segsum[seg][wl][2] = a2; segsum[seg][wl][3] = a3;
    __syncthreads();

    unsigned b0 = 0, b1 = 0, b2 = 0, b3 = 0;
    for (int s2 = 0; s2 < seg; ++s2) {
        b0 += segsum[s2][wl][0]; b1 += segsum[s2][wl][1];
        b2 += segsum[s2][wl][2]; b3 += segsum[s2][wl][3];
    }
    for (int b = 0; b < NBLK / RSEG; ++b) {
        size_t idx = (size_t)(blk0 + b) * NWORDS + w;
        unsigned v = partial[idx];
        partial[idx] = b0 | (b1 << 8) | (b2 << 16) | (b3 << 24);  // u8-safe (totals < 256)
        b0 += v & 255u; b1 += (v >> 8) & 255u;
        b2 += (v >> 16) & 255u; b3 += (v >> 24) & 255u;
    }

    unsigned mySum = 0, myOcc = 0;
    if (seg == RSEG - 1) {            // b0..b3 are now the full per-bin totals
        counts[w * 4 + 0] = b0; counts[w * 4 + 1] = b1;
        counts[w * 4 + 2] = b2; counts[w * 4 + 3] = b3;
        mySum = b0 + b1 + b2 + b3;
        myOcc = (b0 > 0u) + (b1 > 0u) + (b2 > 0u) + (b3 > 0u);
    }
    red[t] = mySum; __syncthreads();
    for (int off = 256; off > 0; off >>= 1) { if (t < off) red[t] += red[t + off]; __syncthreads(); }
    if (t == 0) partC[blockIdx.x] = red[0];
    __syncthreads();
    red[t] = myOcc; __syncthreads();
    for (int off = 256; off > 0; off >>= 1) { if (t < off) red[t] += red[t + off]; __syncthreads(); }
    if (t == 0) partO[blockIdx.x] = red[0];
}

// per-bin starts (bit31 = not-kept), vid assignment, coords/num_points outputs.
// Each block computes its own global base by reducing partC/partO[0..blk).
__global__ __launch_bounds__(256) void k_scan3(const unsigned* __restrict__ counts,
                                               const unsigned* __restrict__ partC,
                                               const unsigned* __restrict__ partO,
                                               unsigned* __restrict__ starts,
                                               unsigned* __restrict__ binof,
                                               float* __restrict__ out) {
    __shared__ unsigned rc[256], ro[256], sc[256], so[256];
    int t = threadIdx.x;
    int bin = blockIdx.x * 256 + t;
    unsigned c = counts[bin];
    unsigned occ = (c > 0u) ? 1u : 0u;

    rc[t] = (t < blockIdx.x) ? partC[t] : 0u;
    ro[t] = (t < blockIdx.x) ? partO[t] : 0u;
    sc[t] = c; so[t] = occ;
    __syncthreads();
    for (int off = 128; off > 0; off >>= 1) {
        if (t < off) { rc[t] += rc[t + off]; ro[t] += ro[t + off]; }
        __syncthreads();
    }
    unsigned baseC = rc[0], baseO = ro[0];
    for (int off = 1; off < 256; off <<= 1) {
        unsigned ac = (t >= off) ? sc[t - off] : 0u;
        unsigned ao = (t >= off) ? so[t - off] : 0u;
        __syncthreads();
        sc[t] += ac; so[t] += ao;
        __syncthreads();
    }
    unsigned st  = baseC + (sc[t] - c);
    unsigned vid = baseO + (so[t] - occ);
    bool kept = occ && (vid < MAXVOX);
    starts[bin] = st | (kept ? 0u : 0x80000000u);
    if (kept) {
        binof[vid] = (unsigned)bin;
        out[COORDS_OFF + vid * 3 + 0] = (float)(bin >> 8);
        out[COORDS_OFF + vid * 3 + 1] = (float)(bin & 255);
        out[COORDS_OFF + vid * 3 + 2] = 0.0f;
        out[NP_OFF + vid] = (float)(c < MAXPTS ? c : MAXPTS);
    }
}

// ---- pass 3: scatter via LDS byte-cursors seeded with per-block prefixes ----
__global__ __launch_bounds__(1024) void k_scatter(const unsigned* __restrict__ bins, int n,
                                                  const unsigned* __restrict__ partial,
                                                  const unsigned* __restrict__ starts,
                                                  unsigned* __restrict__ members) {
    __shared__ unsigned sh[NWORDS];  // 64 KiB byte-cursors, seeded with exclusive prefix
    int t = threadIdx.x, b = blockIdx.x;
    const unsigned* myp = partial + (size_t)b * NWORDS;
    for (int w = t; w < NWORDS; w += 1024) sh[w] = myp[w];
    __syncthreads();

    int chunk = (n + NBLK - 1) / NBLK;
    int s = b * chunk;
    int e = min(n, s + chunk);
    for (int i = s + t; i < e; i += 1024) {
        unsigned v = bins[i];
        if (v == 0xFFFFFFFFu) continue;
        unsigned st = starts[v];
        if (st & 0x80000000u) continue;            // voxel not kept
        unsigned old = atomicAdd(&sh[v >> 2], 1u << ((v & 3u) * 8u));
        unsigned off = (old >> ((v & 3u) * 8u)) & 255u;
        members[st + off] = (unsigned)i;
    }
}

// ---- pass 4: one wave per voxel slot (4/block); exact index rank; zeroes ----
__global__ __launch_bounds__(256) void k_select(
        const unsigned* __restrict__ binof, const unsigned* __restrict__ counts,
        const unsigned* __restrict__ starts, const unsigned* __restrict__ members,
        const float4* __restrict__ pts, float* __restrict__ out) {
    float4* vox = (float4*)out;
    int v = blockIdx.x * 4 + (threadIdx.x >> 6);
    unsigned lane = threadIdx.x & 63u;
    const float4 z4 = {0.0f, 0.0f, 0.0f, 0.0f};
    unsigned bin = binof[v];
    if (bin == 0xFFFFFFFFu) {
        // unused voxel slot: write zeros everywhere (harness poisons d_out)
        if (lane < 32u) vox[(size_t)v * MAXPTS + lane] = z4;
        if (lane < 3u)  out[COORDS_OFF + v * 3 + lane] = 0.0f;
        if (lane == 3u) out[NP_OFF + v] = 0.0f;
        return;
    }
    unsigned m  = counts[bin];
    unsigned mc = m > 256u ? 256u : m;
    unsigned np = m > 32u ? 32u : m;
    unsigned start = starts[bin] & 0x7FFFFFFFu;

    // tail slots [np, 32) are never data-written: zero them (slots < np always filled)
    if (lane >= np && lane < 32u) vox[(size_t)v * MAXPTS + lane] = z4;

    if (mc <= 64u) {
        unsigned e0 = (lane < mc) ? members[start + lane] : 0xFFFFFFFFu;
        unsigned r0 = 0;
        int jm = (int)mc;
        for (int j = 0; j < jm; ++j) {
            unsigned a0 = (unsigned)__shfl((int)e0, j);
            r0 += (a0 < e0);
        }
        if (e0 != 0xFFFFFFFFu && r0 < MAXPTS) vox[(size_t)v * MAXPTS + r0] = pts[e0];
    } else if (mc <= 128u) {
        unsigned e0 = members[start + lane];
        unsigned e1 = (lane + 64u < mc) ? members[start + lane + 64u] : 0xFFFFFFFFu;
        unsigned r0 = 0, r1 = 0;
        for (int j = 0; j < 64; ++j) {
            unsigned a0 = (unsigned)__shfl((int)e0, j);
            unsigned a1 = (unsigned)__shfl((int)e1, j);
            r0 += (a0 < e0) + (a1 < e0);
            r1 += (a0 < e1) + (a1 < e1);
        }
        if (r0 < MAXPTS) vox[(size_t)v * MAXPTS + r0] = pts[e0];
        if (e1 != 0xFFFFFFFFu && r1 < MAXPTS) vox[(size_t)v * MAXPTS + r1] = pts[e1];
    } else {
        unsigned e0 = members[start + lane];
        unsigned e1 = members[start + lane + 64u];
        unsigned e2 = (lane + 128u < mc) ? members[start + lane + 128u] : 0xFFFFFFFFu;
        unsigned e3 = (lane + 192u < mc) ? members[start + lane + 192u] : 0xFFFFFFFFu;
        unsigned r0 = 0, r1 = 0, r2 = 0, r3 = 0;
        for (int j = 0; j < 64; ++j) {
            unsigned a0 = (unsigned)__shfl((int)e0, j);
            unsigned a1 = (unsigned)__shfl((int)e1, j);
            unsigned a2 = (unsigned)__shfl((int)e2, j);
            unsigned a3 = (unsigned)__shfl((int)e3, j);
            r0 += (a0 < e0) + (a1 < e0) + (a2 < e0) + (a3 < e0);
            r1 += (a0 < e1) + (a1 < e1) + (a2 < e1) + (a3 < e1);
            r2 += (a0 < e2) + (a1 < e2) + (a2 < e2) + (a3 < e2);
            r3 += (a0 < e3) + (a1 < e3) + (a2 < e3) + (a3 < e3);
        }
        if (r0 < MAXPTS) vox[(size_t)v * MAXPTS + r0] = pts[e0];
        if (r1 < MAXPTS) vox[(size_t)v * MAXPTS + r1] = pts[e1];
        if (e2 != 0xFFFFFFFFu && r2 < MAXPTS) vox[(size_t)v * MAXPTS + r2] = pts[e2];
        if (e3 != 0xFFFFFFFFu && r3 < MAXPTS) vox[(size_t)v * MAXPTS + r3] = pts[e3];
    }
}

extern "C" void kernel_launch(void* const* d_in, const int* in_sizes, int n_in,
                              void* d_out, int out_size, void* d_ws, size_t ws_size,
                              hipStream_t stream) {
    const float4* pts = (const float4*)d_in[0];
    int n = in_sizes[0] / 4;
    float* out = (float*)d_out;
    char* ws = (char*)d_ws;

    unsigned* counts  = (unsigned*)(ws + OFF_COUNTS);
    unsigned* starts  = (unsigned*)(ws + OFF_STARTS);
    unsigned* binof   = (unsigned*)(ws + OFF_BINOF);
    unsigned* partC   = (unsigned*)(ws + OFF_PARTC);
    unsigned* partO   = (unsigned*)(ws + OFF_PARTO);
    unsigned* bins    = (unsigned*)(ws + OFF_BINS);
    unsigned* partial = (unsigned*)(ws + OFF_PARTIAL);
    unsigned* members = (unsigned*)(ws + OFF_MEMBERS);

    k_hist   <<<NBLK, 1024, 0, stream>>>(pts, n, bins, partial);
    k_reduce <<<NWORDS / 64, 512, 0, stream>>>(partial, counts, partC, partO, binof);
    k_scan3  <<<256, 256, 0, stream>>>(counts, partC, partO, starts, binof, out);
    k_scatter<<<NBLK, 1024, 0, stream>>>(bins, n, partial, starts, members);
    k_select <<<MAXVOX / 4, 256, 0, stream>>>(binof, counts, starts, members, pts, out);
}